// Round 6
// baseline (38.002 us; speedup 1.0000x reference)
//
#include <hip/hip_runtime.h>
#include <hip/hip_fp16.h>
#include <math.h>

#define NPTS 200
#define L33   33
#define NLAT  35937        // 33^3
#define NCELL 32768        // 32^3 cells
#define NPREP (NCELL * 8)  // one thread per (cell, corner)

// ws layout (bytes):
//   [0, 512K)            H    : fp16 8-corner blocks (NCELL * 16 B)
//   [512K, 512K+1M)      C32  : f32  8-corner blocks (NCELL * 32 B)
//   [1.5M, +140.4K)      Tlat : f32 33^3 combined-logit lattice
#define WS_C32_OFF   (NCELL * 16)
#define WS_TLAT_OFF  (WS_C32_OFF + NCELL * 32)

// ---------- trilinear label (channel 0) of grid g at u in [0,R]^3 ----------
template<int R>
__device__ __forceinline__ float tri_label(const float* __restrict__ g,
                                           float ux, float uy, float uz) {
    constexpr int Rp1 = R + 1;
    constexpr int SX  = Rp1 * Rp1;
    int ix = min((int)ux, R - 1);
    int iy = min((int)uy, R - 1);
    int iz = min((int)uz, R - 1);
    float fx = ux - (float)ix, fy = uy - (float)iy, fz = uz - (float)iz;
    int b = (ix * Rp1 + iy) * Rp1 + iz;
    float v000 = g[4*b],            v001 = g[4*(b+1)];
    float v010 = g[4*(b+Rp1)],      v011 = g[4*(b+Rp1+1)];
    float v100 = g[4*(b+SX)],       v101 = g[4*(b+SX+1)];
    float v110 = g[4*(b+SX+Rp1)],   v111 = g[4*(b+SX+Rp1+1)];
    float c00 = fmaf(fz, v001 - v000, v000);
    float c01 = fmaf(fz, v011 - v010, v010);
    float c10 = fmaf(fz, v101 - v100, v100);
    float c11 = fmaf(fz, v111 - v110, v110);
    float c0  = fmaf(fy, c01 - c00, c00);
    float c1  = fmaf(fy, c11 - c10, c10);
    return fmaf(fx, c1 - c0, c0);
}

// ---------- prep1: combined logit at every 33^3 lattice point ----------
__global__ __launch_bounds__(256)
void prep1_kernel(const float* __restrict__ g0, const float* __restrict__ g1,
                  const float* __restrict__ g2, const float* __restrict__ wl,
                  const float* __restrict__ bl, float* __restrict__ T) {
    int i = blockIdx.x * blockDim.x + threadIdx.x;
    if (i >= NLAT) return;
    int jz = i % L33;
    int r  = i / L33;
    int jy = r % L33;
    int jx = r / L33;
    float fx = (float)jx, fy = (float)jy, fz = (float)jz;
    float L0 = tri_label<8 >(g0, fx * 0.25f, fy * 0.25f, fz * 0.25f);  // exact quarters
    float L1 = tri_label<16>(g1, fx * 0.5f,  fy * 0.5f,  fz * 0.5f);   // exact halves
    float L2 = g2[4 * i];
    T[i] = bl[0] + wl[0] * L0 + wl[1] * L1 + wl[2] * L2;
}

// ---------- prep2: pack 8-corner blocks, fp16 (hot) + f32 (refine) ----------
// cell = (iy<<10)|(iz<<5)|ix  (x innermost), corner c = dx*4 + dy*2 + dz
__global__ __launch_bounds__(256)
void prep2_kernel(const float* __restrict__ T, __half* __restrict__ H,
                  float* __restrict__ C) {
    int id = blockIdx.x * blockDim.x + threadIdx.x;
    if (id >= NPREP) return;
    int c    = id & 7;
    int cell = id >> 3;
    int ix = cell & 31;
    int iz = (cell >> 5) & 31;
    int iy = cell >> 10;
    int jx = ix + ((c >> 2) & 1);
    int jy = iy + ((c >> 1) & 1);
    int jz = iz + (c & 1);
    float v = T[(jx * L33 + jy) * L33 + jz];
    C[id] = v;
    H[id] = __float2half(v);
}

// ---------- RGB corner contribution (1 point per ray, corner-parallel) ----------
template<int R>
__device__ __forceinline__ void rgb_corner(const float* __restrict__ g,
                                           float cx, float cy, float cz,
                                           int dx, int dy, int dz,
                                           float* f3) {
    constexpr int Rp1 = R + 1;
    float ux = cx * (float)R, uy = cy * (float)R, uz = cz * (float)R;
    int ix = min((int)ux, R - 1);
    int iy = min((int)uy, R - 1);
    int iz = min((int)uz, R - 1);
    float fx = ux - (float)ix, fy = uy - (float)iy, fz = uz - (float)iz;
    int idx = ((ix + dx) * Rp1 + (iy + dy)) * Rp1 + (iz + dz);
    float w = (dx ? fx : 1.0f - fx) * (dy ? fy : 1.0f - fy) * (dz ? fz : 1.0f - fz);
    float4 v = *reinterpret_cast<const float4*>(g + 4 * idx);
    f3[0] = w * v.y;
    f3[1] = w * v.z;
    f3[2] = w * v.w;
}

// ---------- main: 8 lanes/ray; 1x16B fp16 gather per point; branch-free
// hot loop with suspect-mask + rare f32 refine for sign-exact firsthit ----------
__global__ __launch_bounds__(256, 4)
void rays_kernel(const float* __restrict__ x,
                 const __half* __restrict__ H,
                 const float4* __restrict__ C,
                 const float* __restrict__ g0,
                 const float* __restrict__ g1,
                 const float* __restrict__ g2,
                 const float* __restrict__ wr,
                 const float* __restrict__ br,
                 float* __restrict__ out_hits,
                 float* __restrict__ out_rgb,
                 int n)
{
    const int tid = blockIdx.x * blockDim.x + threadIdx.x;
    const int ray = tid >> 3;
    const int sub = (int)(threadIdx.x & 7);
    if (ray >= n) return;

    const float th1 = x[ray * 4 + 0];
    const float ph1 = x[ray * 4 + 1];
    const float th2 = x[ray * 4 + 2];
    const float ph2 = x[ray * 4 + 3];
    float s1 = __sinf(th1), c1 = __cosf(th1);
    float s2 = __sinf(th2), c2 = __cosf(th2);
    float p1x = s1 * __cosf(ph1), p1y = s1 * __sinf(ph1), p1z = c1;
    float p2x = s2 * __cosf(ph2), p2y = s2 * __sinf(ph2), p2z = c2;
    const float dxr = p2x - p1x, dyr = p2y - p1y, dzr = p2z - p1z;

    const float inv = 1.0f / (float)(NPTS - 1);
    const float sc  = 16.0f * inv;

    const float bx = fmaf(p1x, 16.0f, 16.0f);
    const float by = fmaf(p1y, 16.0f, 16.0f);
    const float bz = fmaf(p1z, 16.0f, 16.0f);
    const float dux = dxr * sc, duy = dyr * sc, duz = dzr * sc;

    const float subf = (float)sub;
    float maxlogit = -INFINITY;
    int fc = NPTS;              // certain first-hit
    unsigned smask = 0u;        // suspect bits (|logit| <= thr), bit i <-> t = 8i+sub

#pragma unroll
    for (int i = 0; i < 25; ++i) {
        float tf = subf + (float)(8 * i);
        float ux = fmaf(tf, dux, bx);
        float uy = fmaf(tf, duy, by);
        float uz = fmaf(tf, duz, bz);
        int ix = min((int)ux, 31);
        int iy = min((int)uy, 31);
        int iz = min((int)uz, 31);
        float fx = ux - (float)ix;
        float fy = uy - (float)iy;
        float fz = uz - (float)iz;
        int idx = (iy << 10) | (iz << 5) | ix;
        uint4 raw = *reinterpret_cast<const uint4*>(
                        reinterpret_cast<const unsigned char*>(H) + ((size_t)idx << 4));
        float2 a00 = __half22float2(*reinterpret_cast<const __half2*>(&raw.x)); // c000,c001
        float2 a01 = __half22float2(*reinterpret_cast<const __half2*>(&raw.y)); // c010,c011
        float2 a10 = __half22float2(*reinterpret_cast<const __half2*>(&raw.z)); // c100,c101
        float2 a11 = __half22float2(*reinterpret_cast<const __half2*>(&raw.w)); // c110,c111
        float b00 = fmaf(fx, a10.x - a00.x, a00.x);
        float b01 = fmaf(fx, a10.y - a00.y, a00.y);
        float b10 = fmaf(fx, a11.x - a01.x, a01.x);
        float b11 = fmaf(fx, a11.y - a01.y, a01.y);
        float r0 = fmaf(fz, b01 - b00, b00);
        float r1 = fmaf(fz, b11 - b10, b10);
        float logit = fmaf(fy, r1 - r0, r0);
        float ma = fmaxf(fmaxf(fmaxf(fabsf(a00.x), fabsf(a00.y)),
                               fmaxf(fabsf(a01.x), fabsf(a01.y))),
                         fmaxf(fmaxf(fabsf(a10.x), fabsf(a10.y)),
                               fmaxf(fabsf(a11.x), fabsf(a11.y))));
        float thr = 1.5e-3f * ma;           // 3x the fp16-rounding error bound
        maxlogit = fmaxf(maxlogit, logit);
        int tcur = 8 * i + sub;
        fc = (logit > thr) ? min(fc, tcur) : fc;
        smask |= (fabsf(logit) <= thr) ? (1u << i) : 0u;
    }

#pragma unroll
    for (int m = 4; m >= 1; m >>= 1) {
        maxlogit = fmaxf(maxlogit, __shfl_xor(maxlogit, m, 64));
        fc = min(fc, __shfl_xor(fc, m, 64));
    }

    // ---- pass 2 (rare): resolve suspects earlier than the certain first-hit ----
    int fh = fc;
    unsigned mm = smask;
    while (mm) {
        int i = __builtin_ctz(mm);
        mm &= mm - 1;
        int t = 8 * i + sub;
        if (t >= fh) break;                 // ascending t: nothing else can matter
        float tf = (float)t;
        float ux = fmaf(tf, dux, bx);
        float uy = fmaf(tf, duy, by);
        float uz = fmaf(tf, duz, bz);
        int ix = min((int)ux, 31);
        int iy = min((int)uy, 31);
        int iz = min((int)uz, 31);
        float fx = ux - (float)ix;
        float fy = uy - (float)iy;
        float fz = uz - (float)iz;
        int idx = (iy << 10) | (iz << 5) | ix;
        const float4* p = C + 2 * idx;
        float4 q0 = p[0];
        float4 q1 = p[1];
        float mx_ = fmaf(fx, q1.x - q0.x, q0.x);
        float my_ = fmaf(fx, q1.y - q0.y, q0.y);
        float mz_ = fmaf(fx, q1.z - q0.z, q0.z);
        float mw_ = fmaf(fx, q1.w - q0.w, q0.w);
        float r0_ = fmaf(fz, my_ - mx_, mx_);
        float r1_ = fmaf(fz, mw_ - mz_, mz_);
        float lg  = fmaf(fy, r1_ - r0_, r0_);
        if (lg > 0.0f) { fh = t; break; }
    }

#pragma unroll
    for (int m = 4; m >= 1; m >>= 1)
        fh = min(fh, __shfl_xor(fh, m, 64));

    // ---- RGB at first-hit point, corner-parallel across the 8 lanes ----
    const int tsel = (fh >= NPTS) ? 0 : fh;
    {
        float tt = (float)tsel * inv;
        float px = fmaf(dxr, tt, p1x);
        float py = fmaf(dyr, tt, p1y);
        float pz = fmaf(dzr, tt, p1z);
        float cx = fminf(fmaxf(fmaf(px, 0.5f, 0.5f), 0.0f), 1.0f);
        float cy = fminf(fmaxf(fmaf(py, 0.5f, 0.5f), 0.0f), 1.0f);
        float cz = fminf(fmaxf(fmaf(pz, 0.5f, 0.5f), 0.0f), 1.0f);
        const int dx = (sub >> 2) & 1, dy = (sub >> 1) & 1, dz = sub & 1;
        float feat[9];
        rgb_corner<8 >(g0, cx, cy, cz, dx, dy, dz, &feat[0]);
        rgb_corner<16>(g1, cx, cy, cz, dx, dy, dz, &feat[3]);
        rgb_corner<32>(g2, cx, cy, cz, dx, dy, dz, &feat[6]);
        float acc[3];
#pragma unroll
        for (int c = 0; c < 3; ++c) {
            float a = 0.0f;
#pragma unroll
            for (int f = 0; f < 9; ++f) a = fmaf(feat[f], wr[f * 3 + c], a);
            acc[c] = a;
        }
#pragma unroll
        for (int m = 4; m >= 1; m >>= 1) {
#pragma unroll
            for (int c = 0; c < 3; ++c)
                acc[c] += __shfl_xor(acc[c], m, 64);
        }
        if (sub == 0) {
            out_hits[ray] = 1.0f / (1.0f + __expf(-maxlogit));
#pragma unroll
            for (int c = 0; c < 3; ++c)
                out_rgb[ray * 3 + c] = 1.0f / (1.0f + __expf(-(acc[c] + br[c])));
        }
    }
}

extern "C" void kernel_launch(void* const* d_in, const int* in_sizes, int n_in,
                              void* d_out, int out_size, void* d_ws, size_t ws_size,
                              hipStream_t stream) {
    const float* x  = (const float*)d_in[0];
    const float* g0 = (const float*)d_in[1];
    const float* g1 = (const float*)d_in[2];
    const float* g2 = (const float*)d_in[3];
    const float* wl = (const float*)d_in[4];
    const float* bl = (const float*)d_in[5];
    const float* wr = (const float*)d_in[6];
    const float* br = (const float*)d_in[7];

    const int n = in_sizes[0] / 4;
    float* out_hits = (float*)d_out;
    float* out_rgb  = (float*)d_out + n;

    __half* H   = (__half*)d_ws;
    float*  C32 = (float*)((char*)d_ws + WS_C32_OFF);
    float*  T   = (float*)((char*)d_ws + WS_TLAT_OFF);

    prep1_kernel<<<(NLAT  + 255) / 256, 256, 0, stream>>>(g0, g1, g2, wl, bl, T);
    prep2_kernel<<<(NPREP + 255) / 256, 256, 0, stream>>>(T, H, C32);

    const int block = 256;             // 32 rays per block
    const int grid = (n * 8 + block - 1) / block;
    rays_kernel<<<grid, block, 0, stream>>>(x, H, (const float4*)C32,
                                            g0, g1, g2, wr, br,
                                            out_hits, out_rgb, n);
}

// Round 7
// 37.472 us; speedup vs baseline: 1.0141x; 1.0141x over previous
//
#include <hip/hip_runtime.h>
#include <hip/hip_fp16.h>
#include <math.h>

#define NPTS 200
#define L33   33
#define NLAT  35937        // 33^3
#define NCELL 32768        // 32^3 cells
#define NPREP (NCELL * 8)  // one thread per (cell, corner)

// ws layout (bytes):
//   [0, 512K)            H    : fp16 8-corner blocks (NCELL * 16 B)
//   [512K, 512K+1M)      C32  : f32  8-corner blocks (NCELL * 32 B)
//   [1.5M, +140.4K)      Tlat : f32 33^3 combined-logit lattice
#define WS_C32_OFF   (NCELL * 16)
#define WS_TLAT_OFF  (WS_C32_OFF + NCELL * 32)

// 16B block of 8 fp16 corners; loaded BY VALUE -> global_load_dwordx4, fields
// stay in VGPRs (no address-taking => no scratch; round-6 lesson).
struct __align__(16) HBlk { __half2 p00, p01, p10, p11; };  // p{dx}{dy}, halves = dz 0/1

// ---------- trilinear label (channel 0) of grid g at u in [0,R]^3 ----------
template<int R>
__device__ __forceinline__ float tri_label(const float* __restrict__ g,
                                           float ux, float uy, float uz) {
    constexpr int Rp1 = R + 1;
    constexpr int SX  = Rp1 * Rp1;
    int ix = min((int)ux, R - 1);
    int iy = min((int)uy, R - 1);
    int iz = min((int)uz, R - 1);
    float fx = ux - (float)ix, fy = uy - (float)iy, fz = uz - (float)iz;
    int b = (ix * Rp1 + iy) * Rp1 + iz;
    float v000 = g[4*b],            v001 = g[4*(b+1)];
    float v010 = g[4*(b+Rp1)],      v011 = g[4*(b+Rp1+1)];
    float v100 = g[4*(b+SX)],       v101 = g[4*(b+SX+1)];
    float v110 = g[4*(b+SX+Rp1)],   v111 = g[4*(b+SX+Rp1+1)];
    float c00 = fmaf(fz, v001 - v000, v000);
    float c01 = fmaf(fz, v011 - v010, v010);
    float c10 = fmaf(fz, v101 - v100, v100);
    float c11 = fmaf(fz, v111 - v110, v110);
    float c0  = fmaf(fy, c01 - c00, c00);
    float c1  = fmaf(fy, c11 - c10, c10);
    return fmaf(fx, c1 - c0, c0);
}

// ---------- prep1: combined logit at every 33^3 lattice point ----------
__global__ __launch_bounds__(128)
void prep1_kernel(const float* __restrict__ g0, const float* __restrict__ g1,
                  const float* __restrict__ g2, const float* __restrict__ wl,
                  const float* __restrict__ bl, float* __restrict__ T) {
    int i = blockIdx.x * blockDim.x + threadIdx.x;
    if (i >= NLAT) return;
    int jz = i % L33;
    int r  = i / L33;
    int jy = r % L33;
    int jx = r / L33;
    float fx = (float)jx, fy = (float)jy, fz = (float)jz;
    float L0 = tri_label<8 >(g0, fx * 0.25f, fy * 0.25f, fz * 0.25f);  // exact quarters
    float L1 = tri_label<16>(g1, fx * 0.5f,  fy * 0.5f,  fz * 0.5f);   // exact halves
    float L2 = g2[4 * i];
    T[i] = bl[0] + wl[0] * L0 + wl[1] * L1 + wl[2] * L2;
}

// ---------- prep2: pack 8-corner blocks, fp16 (hot) + f32 (refine) ----------
// cell = (iy<<10)|(iz<<5)|ix  (x innermost), corner c = dx*4 + dy*2 + dz
__global__ __launch_bounds__(256)
void prep2_kernel(const float* __restrict__ T, __half* __restrict__ H,
                  float* __restrict__ C) {
    int id = blockIdx.x * blockDim.x + threadIdx.x;
    if (id >= NPREP) return;
    int c    = id & 7;
    int cell = id >> 3;
    int ix = cell & 31;
    int iz = (cell >> 5) & 31;
    int iy = cell >> 10;
    int jx = ix + ((c >> 2) & 1);
    int jy = iy + ((c >> 1) & 1);
    int jz = iz + (c & 1);
    float v = T[(jx * L33 + jy) * L33 + jz];
    C[id] = v;
    H[id] = __float2half(v);
}

// ---------- RGB corner contribution (1 point per ray, corner-parallel) ----------
template<int R>
__device__ __forceinline__ void rgb_corner(const float* __restrict__ g,
                                           float cx, float cy, float cz,
                                           int dx, int dy, int dz,
                                           float* f3) {
    constexpr int Rp1 = R + 1;
    float ux = cx * (float)R, uy = cy * (float)R, uz = cz * (float)R;
    int ix = min((int)ux, R - 1);
    int iy = min((int)uy, R - 1);
    int iz = min((int)uz, R - 1);
    float fx = ux - (float)ix, fy = uy - (float)iy, fz = uz - (float)iz;
    int idx = ((ix + dx) * Rp1 + (iy + dy)) * Rp1 + (iz + dz);
    float w = (dx ? fx : 1.0f - fx) * (dy ? fy : 1.0f - fy) * (dz ? fz : 1.0f - fz);
    float4 v = *reinterpret_cast<const float4*>(g + 4 * idx);
    f3[0] = w * v.y;
    f3[1] = w * v.z;
    f3[2] = w * v.w;
}

// ---------- main: 8 lanes/ray; ONE 16B fp16 gather per point; hit/suspect
// bitmasks + rare f32 refine keep firsthit sign-exact ----------
__global__ __launch_bounds__(256, 4)
void rays_kernel(const float* __restrict__ x,
                 const HBlk* __restrict__ H,
                 const float4* __restrict__ C,
                 const float* __restrict__ g0,
                 const float* __restrict__ g1,
                 const float* __restrict__ g2,
                 const float* __restrict__ wr,
                 const float* __restrict__ br,
                 float* __restrict__ out_hits,
                 float* __restrict__ out_rgb,
                 int n)
{
    const int tid = blockIdx.x * blockDim.x + threadIdx.x;
    const int ray = tid >> 3;
    const int sub = (int)(threadIdx.x & 7);
    if (ray >= n) return;

    const float th1 = x[ray * 4 + 0];
    const float ph1 = x[ray * 4 + 1];
    const float th2 = x[ray * 4 + 2];
    const float ph2 = x[ray * 4 + 3];
    float s1 = __sinf(th1), c1 = __cosf(th1);
    float s2 = __sinf(th2), c2 = __cosf(th2);
    float p1x = s1 * __cosf(ph1), p1y = s1 * __sinf(ph1), p1z = c1;
    float p2x = s2 * __cosf(ph2), p2y = s2 * __sinf(ph2), p2z = c2;
    const float dxr = p2x - p1x, dyr = p2y - p1y, dzr = p2z - p1z;

    const float inv = 1.0f / (float)(NPTS - 1);
    const float sc  = 16.0f * inv;

    const float bx = fmaf(p1x, 16.0f, 16.0f);
    const float by = fmaf(p1y, 16.0f, 16.0f);
    const float bz = fmaf(p1z, 16.0f, 16.0f);
    const float dux = dxr * sc, duy = dyr * sc, duz = dzr * sc;

    const float subf = (float)sub;
    float maxlogit = -INFINITY;
    unsigned hmask = 0u;        // certain-hit bits   (logit >  thr), bit i <-> t=8i+sub
    unsigned smask = 0u;        // suspect bits       (|logit| <= thr)

#pragma unroll
    for (int i = 0; i < 25; ++i) {
        float tf = subf + (float)(8 * i);    // exact small ints
        float ux = fmaf(tf, dux, bx);
        float uy = fmaf(tf, duy, by);
        float uz = fmaf(tf, duz, bz);
        int ix = min((int)ux, 31);
        int iy = min((int)uy, 31);
        int iz = min((int)uz, 31);
        float fx = ux - (float)ix;
        float fy = uy - (float)iy;
        float fz = uz - (float)iz;
        int idx = (iy << 10) | (iz << 5) | ix;
        HBlk blk = H[idx];                   // single dwordx4, stays in VGPRs
        float2 a00 = __half22float2(blk.p00);   // c000,c001
        float2 a01 = __half22float2(blk.p01);   // c010,c011
        float2 a10 = __half22float2(blk.p10);   // c100,c101
        float2 a11 = __half22float2(blk.p11);   // c110,c111
        float b00 = fmaf(fx, a10.x - a00.x, a00.x);
        float b01 = fmaf(fx, a10.y - a00.y, a00.y);
        float b10 = fmaf(fx, a11.x - a01.x, a01.x);
        float b11 = fmaf(fx, a11.y - a01.y, a01.y);
        float r0 = fmaf(fz, b01 - b00, b00);
        float r1 = fmaf(fz, b11 - b10, b10);
        float logit = fmaf(fy, r1 - r0, r0);
        // |corner| max: fabs folds into v_max input modifiers (7 ops)
        float ma = fmaxf(fmaxf(fmaxf(fabsf(a00.x), fabsf(a00.y)),
                               fmaxf(fabsf(a01.x), fabsf(a01.y))),
                         fmaxf(fmaxf(fabsf(a10.x), fabsf(a10.y)),
                               fmaxf(fabsf(a11.x), fabsf(a11.y))));
        float thr = fmaf(1.5e-3f, ma, 1e-4f);   // 3x fp16 rel-err + denormal floor
        maxlogit = fmaxf(maxlogit, logit);
        unsigned bit = 1u << i;
        hmask |= (logit > thr)          ? bit : 0u;
        smask |= (fabsf(logit) <= thr)  ? bit : 0u;
    }

    int fc = hmask ? (8 * __builtin_ctz(hmask) + sub) : NPTS;

#pragma unroll
    for (int m = 4; m >= 1; m >>= 1) {
        maxlogit = fmaxf(maxlogit, __shfl_xor(maxlogit, m, 64));
        fc = min(fc, __shfl_xor(fc, m, 64));
    }

    // ---- pass 2 (rare): resolve suspects earlier than the certain first-hit ----
    int fh = fc;
    unsigned mm = smask;
    while (mm) {
        int i = __builtin_ctz(mm);
        mm &= mm - 1;
        int t = 8 * i + sub;
        if (t >= fh) break;                 // ascending t: nothing else can matter
        float tf = (float)t;
        float ux = fmaf(tf, dux, bx);
        float uy = fmaf(tf, duy, by);
        float uz = fmaf(tf, duz, bz);
        int ix = min((int)ux, 31);
        int iy = min((int)uy, 31);
        int iz = min((int)uz, 31);
        float fx = ux - (float)ix;
        float fy = uy - (float)iy;
        float fz = uz - (float)iz;
        int idx = (iy << 10) | (iz << 5) | ix;
        const float4* p = C + 2 * idx;
        float4 q0 = p[0];
        float4 q1 = p[1];
        float mx_ = fmaf(fx, q1.x - q0.x, q0.x);
        float my_ = fmaf(fx, q1.y - q0.y, q0.y);
        float mz_ = fmaf(fx, q1.z - q0.z, q0.z);
        float mw_ = fmaf(fx, q1.w - q0.w, q0.w);
        float r0_ = fmaf(fz, my_ - mx_, mx_);
        float r1_ = fmaf(fz, mw_ - mz_, mz_);
        float lg  = fmaf(fy, r1_ - r0_, r0_);
        if (lg > 0.0f) { fh = t; break; }
    }

#pragma unroll
    for (int m = 4; m >= 1; m >>= 1)
        fh = min(fh, __shfl_xor(fh, m, 64));

    // ---- RGB at first-hit point, corner-parallel across the 8 lanes ----
    const int tsel = (fh >= NPTS) ? 0 : fh;
    {
        float tt = (float)tsel * inv;
        float px = fmaf(dxr, tt, p1x);
        float py = fmaf(dyr, tt, p1y);
        float pz = fmaf(dzr, tt, p1z);
        float cx = fminf(fmaxf(fmaf(px, 0.5f, 0.5f), 0.0f), 1.0f);
        float cy = fminf(fmaxf(fmaf(py, 0.5f, 0.5f), 0.0f), 1.0f);
        float cz = fminf(fmaxf(fmaf(pz, 0.5f, 0.5f), 0.0f), 1.0f);
        const int dx = (sub >> 2) & 1, dy = (sub >> 1) & 1, dz = sub & 1;
        float feat[9];
        rgb_corner<8 >(g0, cx, cy, cz, dx, dy, dz, &feat[0]);
        rgb_corner<16>(g1, cx, cy, cz, dx, dy, dz, &feat[3]);
        rgb_corner<32>(g2, cx, cy, cz, dx, dy, dz, &feat[6]);
        float acc[3];
#pragma unroll
        for (int c = 0; c < 3; ++c) {
            float a = 0.0f;
#pragma unroll
            for (int f = 0; f < 9; ++f) a = fmaf(feat[f], wr[f * 3 + c], a);
            acc[c] = a;
        }
#pragma unroll
        for (int m = 4; m >= 1; m >>= 1) {
#pragma unroll
            for (int c = 0; c < 3; ++c)
                acc[c] += __shfl_xor(acc[c], m, 64);
        }
        if (sub == 0) {
            out_hits[ray] = 1.0f / (1.0f + __expf(-maxlogit));
#pragma unroll
            for (int c = 0; c < 3; ++c)
                out_rgb[ray * 3 + c] = 1.0f / (1.0f + __expf(-(acc[c] + br[c])));
        }
    }
}

extern "C" void kernel_launch(void* const* d_in, const int* in_sizes, int n_in,
                              void* d_out, int out_size, void* d_ws, size_t ws_size,
                              hipStream_t stream) {
    const float* x  = (const float*)d_in[0];
    const float* g0 = (const float*)d_in[1];
    const float* g1 = (const float*)d_in[2];
    const float* g2 = (const float*)d_in[3];
    const float* wl = (const float*)d_in[4];
    const float* bl = (const float*)d_in[5];
    const float* wr = (const float*)d_in[6];
    const float* br = (const float*)d_in[7];

    const int n = in_sizes[0] / 4;
    float* out_hits = (float*)d_out;
    float* out_rgb  = (float*)d_out + n;

    __half* H   = (__half*)d_ws;
    float*  C32 = (float*)((char*)d_ws + WS_C32_OFF);
    float*  T   = (float*)((char*)d_ws + WS_TLAT_OFF);

    prep1_kernel<<<(NLAT + 127) / 128, 128, 0, stream>>>(g0, g1, g2, wl, bl, T);
    prep2_kernel<<<(NPREP + 255) / 256, 256, 0, stream>>>(T, H, C32);

    const int block = 256;             // 32 rays per block
    const int grid = (n * 8 + block - 1) / block;
    rays_kernel<<<grid, block, 0, stream>>>(x, (const HBlk*)H, (const float4*)C32,
                                            g0, g1, g2, wr, br,
                                            out_hits, out_rgb, n);
}

// Round 8
// 34.780 us; speedup vs baseline: 1.0926x; 1.0774x over previous
//
#include <hip/hip_runtime.h>
#include <math.h>

#define NPTS 200
#define L33   33
#define NLAT  35937        // 33^3
#define NCELL 32768        // 32^3 cells
#define NPREP (NCELL * 8)  // one thread per (cell, corner)

// ws layout (bytes):
//   [0, 512K)            H    : bf16 8-corner blocks (NCELL * 16 B)
//   [512K, 512K+1M)      C32  : f32  8-corner blocks (NCELL * 32 B)
//   [1.5M, +140.4K)      Tlat : f32 33^3 combined-logit lattice
#define WS_C32_OFF   (NCELL * 16)
#define WS_TLAT_OFF  (WS_C32_OFF + NCELL * 32)

// ---------- trilinear label (channel 0) of grid g at u in [0,R]^3 ----------
template<int R>
__device__ __forceinline__ float tri_label(const float* __restrict__ g,
                                           float ux, float uy, float uz) {
    constexpr int Rp1 = R + 1;
    constexpr int SX  = Rp1 * Rp1;
    int ix = min((int)ux, R - 1);
    int iy = min((int)uy, R - 1);
    int iz = min((int)uz, R - 1);
    float fx = ux - (float)ix, fy = uy - (float)iy, fz = uz - (float)iz;
    int b = (ix * Rp1 + iy) * Rp1 + iz;
    float v000 = g[4*b],            v001 = g[4*(b+1)];
    float v010 = g[4*(b+Rp1)],      v011 = g[4*(b+Rp1+1)];
    float v100 = g[4*(b+SX)],       v101 = g[4*(b+SX+1)];
    float v110 = g[4*(b+SX+Rp1)],   v111 = g[4*(b+SX+Rp1+1)];
    float c00 = fmaf(fz, v001 - v000, v000);
    float c01 = fmaf(fz, v011 - v010, v010);
    float c10 = fmaf(fz, v101 - v100, v100);
    float c11 = fmaf(fz, v111 - v110, v110);
    float c0  = fmaf(fy, c01 - c00, c00);
    float c1  = fmaf(fy, c11 - c10, c10);
    return fmaf(fx, c1 - c0, c0);
}

// ---------- prep1: combined logit at every 33^3 lattice point ----------
__global__ __launch_bounds__(128)
void prep1_kernel(const float* __restrict__ g0, const float* __restrict__ g1,
                  const float* __restrict__ g2, const float* __restrict__ wl,
                  const float* __restrict__ bl, float* __restrict__ T) {
    int i = blockIdx.x * blockDim.x + threadIdx.x;
    if (i >= NLAT) return;
    int jz = i % L33;
    int r  = i / L33;
    int jy = r % L33;
    int jx = r / L33;
    float fx = (float)jx, fy = (float)jy, fz = (float)jz;
    float L0 = tri_label<8 >(g0, fx * 0.25f, fy * 0.25f, fz * 0.25f);  // exact quarters
    float L1 = tri_label<16>(g1, fx * 0.5f,  fy * 0.5f,  fz * 0.5f);   // exact halves
    float L2 = g2[4 * i];
    T[i] = bl[0] + wl[0] * L0 + wl[1] * L1 + wl[2] * L2;
}

// ---------- prep2: pack 8-corner blocks, bf16-RNE (hot) + f32 (refine) ----------
// cell = (iy<<10)|(iz<<5)|ix  (x innermost), corner c = dx*4 + dy*2 + dz
__global__ __launch_bounds__(256)
void prep2_kernel(const float* __restrict__ T, unsigned short* __restrict__ H,
                  float* __restrict__ C) {
    int id = blockIdx.x * blockDim.x + threadIdx.x;
    if (id >= NPREP) return;
    int c    = id & 7;
    int cell = id >> 3;
    int ix = cell & 31;
    int iz = (cell >> 5) & 31;
    int iy = cell >> 10;
    int jx = ix + ((c >> 2) & 1);
    int jy = iy + ((c >> 1) & 1);
    int jz = iz + (c & 1);
    float v = T[(jx * L33 + jy) * L33 + jz];
    C[id] = v;
    unsigned u = __float_as_uint(v);
    unsigned r = u + 0x7fffu + ((u >> 16) & 1u);   // round-to-nearest-even bf16
    H[id] = (unsigned short)(r >> 16);
}

// ---------- RGB corner contribution (1 point per ray, corner-parallel) ----------
template<int R>
__device__ __forceinline__ void rgb_corner(const float* __restrict__ g,
                                           float cx, float cy, float cz,
                                           int dx, int dy, int dz,
                                           float* f3) {
    constexpr int Rp1 = R + 1;
    float ux = cx * (float)R, uy = cy * (float)R, uz = cz * (float)R;
    int ix = min((int)ux, R - 1);
    int iy = min((int)uy, R - 1);
    int iz = min((int)uz, R - 1);
    float fx = ux - (float)ix, fy = uy - (float)iy, fz = uz - (float)iz;
    int idx = ((ix + dx) * Rp1 + (iy + dy)) * Rp1 + (iz + dz);
    float w = (dx ? fx : 1.0f - fx) * (dy ? fy : 1.0f - fy) * (dz ? fz : 1.0f - fz);
    float4 v = *reinterpret_cast<const float4*>(g + 4 * idx);
    f3[0] = w * v.y;
    f3[1] = w * v.z;
    f3[2] = w * v.w;
}

// ---------- main: 8 lanes/ray; ONE 16B bf16 gather per point, integer unpack
// (no __half classes => no alloca/scratch); hit/suspect masks + rare f32 refine ----------
__global__ __launch_bounds__(256, 4)
void rays_kernel(const float* __restrict__ x,
                 const uint4* __restrict__ H4,
                 const float4* __restrict__ C,
                 const float* __restrict__ g0,
                 const float* __restrict__ g1,
                 const float* __restrict__ g2,
                 const float* __restrict__ wr,
                 const float* __restrict__ br,
                 float* __restrict__ out_hits,
                 float* __restrict__ out_rgb,
                 int n)
{
    const int tid = blockIdx.x * blockDim.x + threadIdx.x;
    const int ray = tid >> 3;
    const int sub = (int)(threadIdx.x & 7);
    if (ray >= n) return;

    const float th1 = x[ray * 4 + 0];
    const float ph1 = x[ray * 4 + 1];
    const float th2 = x[ray * 4 + 2];
    const float ph2 = x[ray * 4 + 3];
    float s1 = __sinf(th1), c1 = __cosf(th1);
    float s2 = __sinf(th2), c2 = __cosf(th2);
    float p1x = s1 * __cosf(ph1), p1y = s1 * __sinf(ph1), p1z = c1;
    float p2x = s2 * __cosf(ph2), p2y = s2 * __sinf(ph2), p2z = c2;
    const float dxr = p2x - p1x, dyr = p2y - p1y, dzr = p2z - p1z;

    const float inv = 1.0f / (float)(NPTS - 1);
    const float sc  = 16.0f * inv;

    const float bx = fmaf(p1x, 16.0f, 16.0f);
    const float by = fmaf(p1y, 16.0f, 16.0f);
    const float bz = fmaf(p1z, 16.0f, 16.0f);
    const float dux = dxr * sc, duy = dyr * sc, duz = dzr * sc;

    const float subf = (float)sub;
    float maxlogit = -INFINITY;
    unsigned hmask = 0u;        // certain-hit bits (logit >  thr), bit i <-> t=8i+sub
    unsigned smask = 0u;        // suspect bits     (|logit| <= thr)

#pragma unroll
    for (int i = 0; i < 25; ++i) {
        float tf = subf + (float)(8 * i);    // exact small ints
        float ux = fmaf(tf, dux, bx);
        float uy = fmaf(tf, duy, by);
        float uz = fmaf(tf, duz, bz);
        int ix = min((int)ux, 31);
        int iy = min((int)uy, 31);
        int iz = min((int)uz, 31);
        float fx = ux - (float)ix;
        float fy = uy - (float)iy;
        float fz = uz - (float)iz;
        int idx = (iy << 10) | (iz << 5) | ix;
        uint4 raw = H4[idx];                 // single dwordx4, stays in VGPRs
        // bf16 unpack: pure integer ops + bitcast, nothing address-taken
        float c000 = __uint_as_float(raw.x << 16);
        float c001 = __uint_as_float(raw.x & 0xffff0000u);
        float c010 = __uint_as_float(raw.y << 16);
        float c011 = __uint_as_float(raw.y & 0xffff0000u);
        float c100 = __uint_as_float(raw.z << 16);
        float c101 = __uint_as_float(raw.z & 0xffff0000u);
        float c110 = __uint_as_float(raw.w << 16);
        float c111 = __uint_as_float(raw.w & 0xffff0000u);
        float b00 = fmaf(fx, c100 - c000, c000);
        float b01 = fmaf(fx, c101 - c001, c001);
        float b10 = fmaf(fx, c110 - c010, c010);
        float b11 = fmaf(fx, c111 - c011, c011);
        float r0 = fmaf(fz, b01 - b00, b00);
        float r1 = fmaf(fz, b11 - b10, b10);
        float logit = fmaf(fy, r1 - r0, r0);
        // |corner| max: fabs folds into v_max input modifiers
        float ma = fmaxf(fmaxf(fmaxf(fabsf(c000), fabsf(c001)),
                               fmaxf(fabsf(c010), fabsf(c011))),
                         fmaxf(fmaxf(fabsf(c100), fabsf(c101)),
                               fmaxf(fabsf(c110), fabsf(c111))));
        float thr = fmaf(4e-3f, ma, 1e-5f);  // 2x bf16-RNE rel-err bound + floor
        maxlogit = fmaxf(maxlogit, logit);
        unsigned bit = 1u << i;
        hmask |= (logit > thr)         ? bit : 0u;
        smask |= (fabsf(logit) <= thr) ? bit : 0u;
    }

    int fc = hmask ? (8 * __builtin_ctz(hmask) + sub) : NPTS;

#pragma unroll
    for (int m = 4; m >= 1; m >>= 1) {
        maxlogit = fmaxf(maxlogit, __shfl_xor(maxlogit, m, 64));
        fc = min(fc, __shfl_xor(fc, m, 64));
    }

    // ---- pass 2 (rare): resolve suspects earlier than the certain first-hit ----
    int fh = fc;
    unsigned mm = smask;
    while (mm) {
        int i = __builtin_ctz(mm);
        mm &= mm - 1;
        int t = 8 * i + sub;
        if (t >= fh) break;                  // ascending t: nothing else can matter
        float tf = (float)t;
        float ux = fmaf(tf, dux, bx);
        float uy = fmaf(tf, duy, by);
        float uz = fmaf(tf, duz, bz);
        int ix = min((int)ux, 31);
        int iy = min((int)uy, 31);
        int iz = min((int)uz, 31);
        float fx = ux - (float)ix;
        float fy = uy - (float)iy;
        float fz = uz - (float)iz;
        int idx = (iy << 10) | (iz << 5) | ix;
        const float4* p = C + 2 * idx;
        float4 q0 = p[0];
        float4 q1 = p[1];
        float mx_ = fmaf(fx, q1.x - q0.x, q0.x);
        float my_ = fmaf(fx, q1.y - q0.y, q0.y);
        float mz_ = fmaf(fx, q1.z - q0.z, q0.z);
        float mw_ = fmaf(fx, q1.w - q0.w, q0.w);
        float r0_ = fmaf(fz, my_ - mx_, mx_);
        float r1_ = fmaf(fz, mw_ - mz_, mz_);
        float lg  = fmaf(fy, r1_ - r0_, r0_);
        if (lg > 0.0f) { fh = t; break; }
    }

#pragma unroll
    for (int m = 4; m >= 1; m >>= 1)
        fh = min(fh, __shfl_xor(fh, m, 64));

    // ---- RGB at first-hit point, corner-parallel across the 8 lanes ----
    const int tsel = (fh >= NPTS) ? 0 : fh;
    {
        float tt = (float)tsel * inv;
        float px = fmaf(dxr, tt, p1x);
        float py = fmaf(dyr, tt, p1y);
        float pz = fmaf(dzr, tt, p1z);
        float cx = fminf(fmaxf(fmaf(px, 0.5f, 0.5f), 0.0f), 1.0f);
        float cy = fminf(fmaxf(fmaf(py, 0.5f, 0.5f), 0.0f), 1.0f);
        float cz = fminf(fmaxf(fmaf(pz, 0.5f, 0.5f), 0.0f), 1.0f);
        const int dx = (sub >> 2) & 1, dy = (sub >> 1) & 1, dz = sub & 1;
        float feat[9];
        rgb_corner<8 >(g0, cx, cy, cz, dx, dy, dz, &feat[0]);
        rgb_corner<16>(g1, cx, cy, cz, dx, dy, dz, &feat[3]);
        rgb_corner<32>(g2, cx, cy, cz, dx, dy, dz, &feat[6]);
        float acc[3];
#pragma unroll
        for (int c = 0; c < 3; ++c) {
            float a = 0.0f;
#pragma unroll
            for (int f = 0; f < 9; ++f) a = fmaf(feat[f], wr[f * 3 + c], a);
            acc[c] = a;
        }
#pragma unroll
        for (int m = 4; m >= 1; m >>= 1) {
#pragma unroll
            for (int c = 0; c < 3; ++c)
                acc[c] += __shfl_xor(acc[c], m, 64);
        }
        if (sub == 0) {
            out_hits[ray] = 1.0f / (1.0f + __expf(-maxlogit));
#pragma unroll
            for (int c = 0; c < 3; ++c)
                out_rgb[ray * 3 + c] = 1.0f / (1.0f + __expf(-(acc[c] + br[c])));
        }
    }
}

extern "C" void kernel_launch(void* const* d_in, const int* in_sizes, int n_in,
                              void* d_out, int out_size, void* d_ws, size_t ws_size,
                              hipStream_t stream) {
    const float* x  = (const float*)d_in[0];
    const float* g0 = (const float*)d_in[1];
    const float* g1 = (const float*)d_in[2];
    const float* g2 = (const float*)d_in[3];
    const float* wl = (const float*)d_in[4];
    const float* bl = (const float*)d_in[5];
    const float* wr = (const float*)d_in[6];
    const float* br = (const float*)d_in[7];

    const int n = in_sizes[0] / 4;
    float* out_hits = (float*)d_out;
    float* out_rgb  = (float*)d_out + n;

    unsigned short* H = (unsigned short*)d_ws;
    float* C32 = (float*)((char*)d_ws + WS_C32_OFF);
    float* T   = (float*)((char*)d_ws + WS_TLAT_OFF);

    prep1_kernel<<<(NLAT + 127) / 128, 128, 0, stream>>>(g0, g1, g2, wl, bl, T);
    prep2_kernel<<<(NPREP + 255) / 256, 256, 0, stream>>>(T, H, C32);

    const int block = 256;             // 32 rays per block
    const int grid = (n * 8 + block - 1) / block;
    rays_kernel<<<grid, block, 0, stream>>>(x, (const uint4*)H, (const float4*)C32,
                                            g0, g1, g2, wr, br,
                                            out_hits, out_rgb, n);
}